// Round 14
// baseline (175.185 us; speedup 1.0000x reference)
//
#include <hip/hip_runtime.h>

#define NB     8192
#define HDIM   64
#define SEQ    180
#define MT     16     // batch rows per block
#define SB     72     // bf16 LDS row stride: 144 B, 16B-aligned (SB=68 regressed: misaligned b128)
#define XSP    100    // xs prologue row stride (floats)
#define OSP    364    // ostage row stride (dwords): 4|364 -> aligned f32x4 copy; duty writes <=2-way

typedef __bf16 bf16x8 __attribute__((ext_vector_type(8)));
typedef __bf16 bf16x4 __attribute__((ext_vector_type(4)));
typedef float  f32x4  __attribute__((ext_vector_type(4)));

#define L2E 1.44269504088896340736f

__device__ __forceinline__ float tanh_f(float x) {
    float e = __builtin_amdgcn_exp2f((2.0f * L2E) * x);
    return 1.0f - 2.0f * __builtin_amdgcn_rcpf(1.0f + e);
}

#define MFMA __builtin_amdgcn_mfma_f32_16x16x32_bf16

// R14 = R13 (114us proven: transposed G^T = W·h^T, plain-bf16 W, fp32 carry,
// packed epilogue, b64 state writes) + LDS output staging: NO global stores
// inside the time loop, so the per-step __syncthreads drains only lgkmcnt
// instead of waiting ~150-300 cyc for L2 store-acks on the duty wave (which
// gates the whole block). One coalesced bulk copy in the epilogue.
__global__ __launch_bounds__(256) void gru_all(
        const float* __restrict__ z, const int* __restrict__ labels,
        const float* __restrict__ embed_w, const float* __restrict__ fc_w,
        const float* __restrict__ fc_b, const float* __restrict__ w_hh,
        const float* __restrict__ b_ih, const float* __restrict__ b_hh,
        const float* __restrict__ out_w, const float* __restrict__ out_b,
        float* __restrict__ out) {
    __shared__ __align__(16) __bf16 hbuf[2][MT * SB];  // [buf] bf16(h)
    __shared__ __align__(16) float  ostage[MT * OSP];  // [row][step*2+o]
    __shared__ __align__(16) float  xs[MT * XSP];      // h0 input [z|embed]

    const int t = threadIdx.x;
    const int w = t >> 6;          // wave 0..3
    const int l = t & 63;
    const int q = l >> 4;          // quad 0..3
    const int n16 = l & 15;
    const int jg = 16 * w + n16;   // W row this lane loads (A-frag m-index)
    const int jb = 16 * w + 4 * q; // first of the 4 h-cols this lane epilogues
    const int bbase = blockIdx.x * MT;

    // ---- prologue A: stage x = [z, embed(labels)] for 16 rows into LDS ----
    for (int c = t; c < MT * 24; c += 256) {    // 24 f32x4 chunks per row
        int m = c / 24, kk = (c % 24) * 4;
        f32x4 v;
        if (kk < 32) v = *(const f32x4*)(z + (size_t)(bbase + m) * 32 + kk);
        else         v = *(const f32x4*)(embed_w + labels[bbase + m] * 64 + (kk - 32));
        *(f32x4*)(xs + m * XSP + kk) = v;
    }

    // ---- persistent w_hh fragments, plain bf16 (MFMA A-operands) ----
    // A[m = n16][k = q*8+j + 32ks] = w_hh[g*64 + jg][k]
    bf16x8 whi[3][2];
#pragma unroll
    for (int g = 0; g < 3; ++g) {
        const float* pr = w_hh + (g * 64 + jg) * HDIM;
#pragma unroll
        for (int ks = 0; ks < 2; ++ks) {
            const float* p = pr + ks * 32 + q * 8;
            f32x4 va = *(const f32x4*)(p);
            f32x4 vb = *(const f32x4*)(p + 4);
#pragma unroll
            for (int j2 = 0; j2 < 4; ++j2) {
                whi[g][ks][j2]     = (__bf16)va[j2];
                whi[g][ks][4 + j2] = (__bf16)vb[j2];
            }
        }
    }

    // ---- output-head A fragments: A[m=n16][k] = out_w[n16][k] (n16<2 live) --
    bf16x8 obhi[2];
#pragma unroll
    for (int ks = 0; ks < 2; ++ks) {
        f32x4 va = {0.f, 0.f, 0.f, 0.f}, vb = {0.f, 0.f, 0.f, 0.f};
        if (n16 < 2) {
            va = *(const f32x4*)(out_w + n16 * 64 + ks * 32 + q * 8);
            vb = *(const f32x4*)(out_w + n16 * 64 + ks * 32 + q * 8 + 4);
        }
#pragma unroll
        for (int j2 = 0; j2 < 4; ++j2) {
            obhi[ks][j2]     = (__bf16)va[j2];
            obhi[ks][4 + j2] = (__bf16)vb[j2];
        }
    }
    // C/D bias by m-row (out-col): live rows m=0,1 sit at q==0, reg r=0,1
    const f32x4 obias = (q == 0) ? f32x4{out_b[0], out_b[1], 0.f, 0.f}
                                 : f32x4{0.f, 0.f, 0.f, 0.f};
    const f32x4 kZ = {0.f, 0.f, 0.f, 0.f};
    const f32x4 one4 = {1.f, 1.f, 1.f, 1.f};

    // per-lane gate constants: vectors over the lane's 4 cols jb..jb+3
    const f32x4 bihR = *(const f32x4*)(b_ih + jb);
    const f32x4 bhhR = *(const f32x4*)(b_hh + jb);
    const f32x4 bihZ = *(const f32x4*)(b_ih + 64 + jb);
    const f32x4 bhhZ = *(const f32x4*)(b_hh + 64 + jb);
    const f32x4 cR4 = (bihR + bhhR) * (-L2E);
    const f32x4 cZ4 = (bihZ + bhhZ) * (-L2E);
    const f32x4 bn4 = *(const f32x4*)(b_hh + 128 + jb);
    const f32x4 cN4 = (*(const f32x4*)(b_ih + 128 + jb)) * (2.0f * L2E);

    const int rdoff = n16 * SB + q * 8;    // h B-frag offset (16B-aligned)
    const int wboff = n16 * SB + jb;       // state-write offset (8B-aligned)
    const int osb   = n16 * OSP;           // ostage row base for this lane

    __syncthreads();   // xs ready

    // ---- prologue B: h0 = tanh(fc_b + fc_w . x); lane -> row n16, 4 cols ----
    f32x4 hprev;
    {
        f32x4 a = *(const f32x4*)(fc_b + jb);
        for (int kc = 0; kc < 24; ++kc) {
            f32x4 xv = *(const f32x4*)(xs + n16 * XSP + kc * 4);
#pragma unroll
            for (int r = 0; r < 4; ++r) {
                f32x4 wv = *(const f32x4*)(fc_w + (size_t)(jb + r) * 96 + kc * 4);
                a[r] += wv[0] * xv[0] + wv[1] * xv[1] + wv[2] * xv[2] + wv[3] * xv[3];
            }
        }
        bf16x4 hp;
#pragma unroll
        for (int r = 0; r < 4; ++r) {
            hprev[r] = tanh_f(a[r]);
            hp[r] = (__bf16)hprev[r];
        }
        *(bf16x4*)(hbuf[0] + wboff) = hp;   // one ds_write_b64
    }
    __syncthreads();   // state 0 published in buf 0

    // Anti-phase the two co-resident blocks (i and i+256 share a CU).
    if ((blockIdx.x >> 8) & 1) __builtin_amdgcn_s_sleep(8);

    for (int u = 0; u < SEQ / 4; ++u) {
#pragma unroll
        for (int s = 0; s < 4; ++s) {
            const int p = s & 1;
            const __bf16* Hh = hbuf[p];
            __bf16* Nh = hbuf[1 - p];

            // h B-frags of state i = 4u+s: B[k=q*8+j][n16] = h[n16][k]
            bf16x8 b0 = *(const bf16x8*)(Hh + rdoff);
            bf16x8 b1 = *(const bf16x8*)(Hh + rdoff + 32);

            // output row i-1 (state i) on static duty wave (s+3)&3 -> LDS only
            if ((u | s) != 0 && w == ((s + 3) & 3)) {
                f32x4 o = obias;
                o = MFMA(obhi[0], b0, o, 0, 0, 0);
                o = MFMA(obhi[1], b1, o, 0, 0, 0);
                if (q == 0)
                    *(float2*)(ostage + osb + (8 * u + 2 * s - 2)) =
                        make_float2(o[0], o[1]);
            }

            // gates: G^T = W·h^T, 2-deep chain per gate
            f32x4 aR, aZ, aN;
            aR = MFMA(whi[0][0], b0, kZ, 0, 0, 0);
            aZ = MFMA(whi[1][0], b0, kZ, 0, 0, 0);
            aN = MFMA(whi[2][0], b0, kZ, 0, 0, 0);
            aR = MFMA(whi[0][1], b1, aR, 0, 0, 0);
            aZ = MFMA(whi[1][1], b1, aZ, 0, 0, 0);
            aN = MFMA(whi[2][1], b1, aN, 0, 0, 0);

            // epilogue: lane's 4 cols of row n16; non-trans math packed f32x4
            f32x4 tR = aR * (-L2E) + cR4;
            f32x4 tZ = aZ * (-L2E) + cZ4;
            f32x4 eR, eZ;
#pragma unroll
            for (int r = 0; r < 4; ++r) {
                eR[r] = __builtin_amdgcn_exp2f(tR[r]);
                eZ[r] = __builtin_amdgcn_exp2f(tZ[r]);
            }
            eR = eR + one4;
            eZ = eZ + one4;
            f32x4 rg, zg;
#pragma unroll
            for (int r = 0; r < 4; ++r) {
                rg[r] = __builtin_amdgcn_rcpf(eR[r]);
                zg[r] = __builtin_amdgcn_rcpf(eZ[r]);
            }
            f32x4 mm = aN + bn4;
            f32x4 tN = (rg * mm) * (2.0f * L2E) + cN4;
            f32x4 eN;
#pragma unroll
            for (int r = 0; r < 4; ++r) eN[r] = __builtin_amdgcn_exp2f(tN[r]);
            eN = eN + one4;
            f32x4 dd;
#pragma unroll
            for (int r = 0; r < 4; ++r) dd[r] = __builtin_amdgcn_rcpf(eN[r]);
            f32x4 ng = dd * (-2.0f) + one4;
            f32x4 hn = zg * (hprev - ng) + ng;   // exact fp32 carry
            hprev = hn;
            bf16x4 hp;
#pragma unroll
            for (int r = 0; r < 4; ++r) hp[r] = (__bf16)hn[r];
            *(bf16x4*)(Nh + wboff) = hp;         // one ds_write_b64

            __syncthreads();   // state i+1 published (LDS-only drain)
        }
    }

    // final output: row 179 (state 180, in buf 0), duty wave 3 -> LDS
    if (w == 3) {
        const __bf16* Hh = hbuf[0];
        bf16x8 b0 = *(const bf16x8*)(Hh + rdoff);
        bf16x8 b1 = *(const bf16x8*)(Hh + rdoff + 32);
        f32x4 o = obias;
        o = MFMA(obhi[0], b0, o, 0, 0, 0);
        o = MFMA(obhi[1], b1, o, 0, 0, 0);
        if (q == 0)
            *(float2*)(ostage + osb + 358) = make_float2(o[0], o[1]);
    }
    __syncthreads();   // all outputs staged

    // ---- epilogue: coalesced bulk copy ostage -> out ([16][360] region) ----
    float* ob = out + (size_t)bbase * (SEQ * 2);
    for (int c = t; c < MT * 90; c += 256) {     // 90 f32x4 chunks per row
        int m = c / 90;
        int o4 = (c - m * 90) * 4;
        f32x4 v = *(const f32x4*)(ostage + m * OSP + o4);
        *(f32x4*)(ob + m * 360 + o4) = v;
    }
}

extern "C" void kernel_launch(void* const* d_in, const int* in_sizes, int n_in,
                              void* d_out, int out_size, void* d_ws, size_t ws_size,
                              hipStream_t stream) {
    (void)in_sizes; (void)n_in; (void)out_size; (void)d_ws; (void)ws_size;
    const float* z       = (const float*)d_in[0];
    const int*   labels  = (const int*)d_in[1];
    const float* embed_w = (const float*)d_in[2];
    const float* fc_w    = (const float*)d_in[3];
    const float* fc_b    = (const float*)d_in[4];
    // d_in[5] = w_ih: unused (GRU input is all zeros; b_ih carries the effect)
    const float* w_hh    = (const float*)d_in[6];
    const float* b_ih    = (const float*)d_in[7];
    const float* b_hh    = (const float*)d_in[8];
    const float* out_w   = (const float*)d_in[9];
    const float* out_b   = (const float*)d_in[10];
    float* out = (float*)d_out;

    gru_all<<<NB / MT, 256, 0, stream>>>(z, labels, embed_w, fc_w, fc_b,
                                         w_hh, b_ih, b_hh, out_w, out_b, out);
}

// Round 15
// 170.102 us; speedup vs baseline: 1.0299x; 1.0299x over previous
//
#include <hip/hip_runtime.h>

#define NB     8192
#define HDIM   64
#define SEQ    180
#define MT     16     // batch rows per block
#define SB     72     // bf16 LDS row stride: 144 B, 16B-aligned (SB=68 regressed: misaligned b128)
#define XSP    100    // xs prologue row stride (floats)

typedef __bf16 bf16x8 __attribute__((ext_vector_type(8)));
typedef __bf16 bf16x4 __attribute__((ext_vector_type(4)));
typedef float  f32x4  __attribute__((ext_vector_type(4)));

#define L2E 1.44269504088896340736f

__device__ __forceinline__ float tanh_f(float x) {
    float e = __builtin_amdgcn_exp2f((2.0f * L2E) * x);
    return 1.0f - 2.0f * __builtin_amdgcn_rcpf(1.0f + e);
}

#define MFMA __builtin_amdgcn_mfma_f32_16x16x32_bf16

// R15 = R13 (114us proven: transposed G^T = W·h^T, plain-bf16 W, fp32 carry,
// packed epilogue, b64 state writes, direct global output stores) + wave
// balance: ALL 4 waves compute the output head redundantly each step (each
// stores only its 4 rows), and the head runs AFTER the state ds_write so it
// issues in the lgkm-drain/barrier shadow. Removes the duty-wave straggler
// that the per-step barrier re-synchronized to 180 times.
__global__ __launch_bounds__(256) void gru_all(
        const float* __restrict__ z, const int* __restrict__ labels,
        const float* __restrict__ embed_w, const float* __restrict__ fc_w,
        const float* __restrict__ fc_b, const float* __restrict__ w_hh,
        const float* __restrict__ b_ih, const float* __restrict__ b_hh,
        const float* __restrict__ out_w, const float* __restrict__ out_b,
        float* __restrict__ out) {
    __shared__ __align__(16) __bf16 hbuf[2][MT * SB];  // [buf] bf16(h)
    __shared__ __align__(16) float  xs[MT * XSP];      // h0 input [z|embed]

    const int t = threadIdx.x;
    const int w = t >> 6;          // wave 0..3
    const int l = t & 63;
    const int q = l >> 4;          // quad 0..3
    const int n16 = l & 15;
    const int jg = 16 * w + n16;   // W row this lane loads (A-frag m-index)
    const int jb = 16 * w + 4 * q; // first of the 4 h-cols this lane epilogues
    const int bbase = blockIdx.x * MT;

    // ---- prologue A: stage x = [z, embed(labels)] for 16 rows into LDS ----
    for (int c = t; c < MT * 24; c += 256) {    // 24 f32x4 chunks per row
        int m = c / 24, kk = (c % 24) * 4;
        f32x4 v;
        if (kk < 32) v = *(const f32x4*)(z + (size_t)(bbase + m) * 32 + kk);
        else         v = *(const f32x4*)(embed_w + labels[bbase + m] * 64 + (kk - 32));
        *(f32x4*)(xs + m * XSP + kk) = v;
    }

    // ---- persistent w_hh fragments, plain bf16 (MFMA A-operands) ----
    // A[m = n16][k = q*8+j + 32ks] = w_hh[g*64 + jg][k]
    bf16x8 whi[3][2];
#pragma unroll
    for (int g = 0; g < 3; ++g) {
        const float* pr = w_hh + (g * 64 + jg) * HDIM;
#pragma unroll
        for (int ks = 0; ks < 2; ++ks) {
            const float* p = pr + ks * 32 + q * 8;
            f32x4 va = *(const f32x4*)(p);
            f32x4 vb = *(const f32x4*)(p + 4);
#pragma unroll
            for (int j2 = 0; j2 < 4; ++j2) {
                whi[g][ks][j2]     = (__bf16)va[j2];
                whi[g][ks][4 + j2] = (__bf16)vb[j2];
            }
        }
    }

    // ---- output-head A fragments: A[m=n16][k] = out_w[n16][k] (n16<2 live) --
    bf16x8 obhi[2];
#pragma unroll
    for (int ks = 0; ks < 2; ++ks) {
        f32x4 va = {0.f, 0.f, 0.f, 0.f}, vb = {0.f, 0.f, 0.f, 0.f};
        if (n16 < 2) {
            va = *(const f32x4*)(out_w + n16 * 64 + ks * 32 + q * 8);
            vb = *(const f32x4*)(out_w + n16 * 64 + ks * 32 + q * 8 + 4);
        }
#pragma unroll
        for (int j2 = 0; j2 < 4; ++j2) {
            obhi[ks][j2]     = (__bf16)va[j2];
            obhi[ks][4 + j2] = (__bf16)vb[j2];
        }
    }
    // C/D bias by m-row (out-col): live rows m=0,1 sit at q==0, reg r=0,1
    const f32x4 obias = (q == 0) ? f32x4{out_b[0], out_b[1], 0.f, 0.f}
                                 : f32x4{0.f, 0.f, 0.f, 0.f};
    const f32x4 kZ = {0.f, 0.f, 0.f, 0.f};
    const f32x4 one4 = {1.f, 1.f, 1.f, 1.f};

    // every wave stores output for its 4 rows: q==0 lane, rows 4w..4w+3
    const bool ostorer = (q == 0) && ((n16 >> 2) == w);

    // per-lane gate constants: vectors over the lane's 4 cols jb..jb+3
    const f32x4 bihR = *(const f32x4*)(b_ih + jb);
    const f32x4 bhhR = *(const f32x4*)(b_hh + jb);
    const f32x4 bihZ = *(const f32x4*)(b_ih + 64 + jb);
    const f32x4 bhhZ = *(const f32x4*)(b_hh + 64 + jb);
    const f32x4 cR4 = (bihR + bhhR) * (-L2E);
    const f32x4 cZ4 = (bihZ + bhhZ) * (-L2E);
    const f32x4 bn4 = *(const f32x4*)(b_hh + 128 + jb);
    const f32x4 cN4 = (*(const f32x4*)(b_ih + 128 + jb)) * (2.0f * L2E);

    const int rdoff = n16 * SB + q * 8;    // h B-frag offset (16B-aligned)
    const int wboff = n16 * SB + jb;       // state-write offset (8B-aligned)
    float* opb = out + (size_t)(bbase + n16) * (SEQ * 2);  // this lane's row

    __syncthreads();   // xs ready

    // ---- prologue B: h0 = tanh(fc_b + fc_w . x); lane -> row n16, 4 cols ----
    f32x4 hprev;
    {
        f32x4 a = *(const f32x4*)(fc_b + jb);
        for (int kc = 0; kc < 24; ++kc) {
            f32x4 xv = *(const f32x4*)(xs + n16 * XSP + kc * 4);
#pragma unroll
            for (int r = 0; r < 4; ++r) {
                f32x4 wv = *(const f32x4*)(fc_w + (size_t)(jb + r) * 96 + kc * 4);
                a[r] += wv[0] * xv[0] + wv[1] * xv[1] + wv[2] * xv[2] + wv[3] * xv[3];
            }
        }
        bf16x4 hp;
#pragma unroll
        for (int r = 0; r < 4; ++r) {
            hprev[r] = tanh_f(a[r]);
            hp[r] = (__bf16)hprev[r];
        }
        *(bf16x4*)(hbuf[0] + wboff) = hp;   // one ds_write_b64
    }
    __syncthreads();   // state 0 published in buf 0

    // Anti-phase the two co-resident blocks (i and i+256 share a CU).
    if ((blockIdx.x >> 8) & 1) __builtin_amdgcn_s_sleep(8);

    for (int u = 0; u < SEQ / 4; ++u) {
#pragma unroll
        for (int s = 0; s < 4; ++s) {
            const int p = s & 1;
            const __bf16* Hh = hbuf[p];
            __bf16* Nh = hbuf[1 - p];

            // h B-frags of state i = 4u+s: B[k=q*8+j][n16] = h[n16][k]
            bf16x8 b0 = *(const bf16x8*)(Hh + rdoff);
            bf16x8 b1 = *(const bf16x8*)(Hh + rdoff + 32);

            // gates: G^T = W·h^T, 2-deep chain per gate
            f32x4 aR, aZ, aN;
            aR = MFMA(whi[0][0], b0, kZ, 0, 0, 0);
            aZ = MFMA(whi[1][0], b0, kZ, 0, 0, 0);
            aN = MFMA(whi[2][0], b0, kZ, 0, 0, 0);
            aR = MFMA(whi[0][1], b1, aR, 0, 0, 0);
            aZ = MFMA(whi[1][1], b1, aZ, 0, 0, 0);
            aN = MFMA(whi[2][1], b1, aN, 0, 0, 0);

            // epilogue: lane's 4 cols of row n16; non-trans math packed f32x4
            f32x4 tR = aR * (-L2E) + cR4;
            f32x4 tZ = aZ * (-L2E) + cZ4;
            f32x4 eR, eZ;
#pragma unroll
            for (int r = 0; r < 4; ++r) {
                eR[r] = __builtin_amdgcn_exp2f(tR[r]);
                eZ[r] = __builtin_amdgcn_exp2f(tZ[r]);
            }
            eR = eR + one4;
            eZ = eZ + one4;
            f32x4 rg, zg;
#pragma unroll
            for (int r = 0; r < 4; ++r) {
                rg[r] = __builtin_amdgcn_rcpf(eR[r]);
                zg[r] = __builtin_amdgcn_rcpf(eZ[r]);
            }
            f32x4 mm = aN + bn4;
            f32x4 tN = (rg * mm) * (2.0f * L2E) + cN4;
            f32x4 eN;
#pragma unroll
            for (int r = 0; r < 4; ++r) eN[r] = __builtin_amdgcn_exp2f(tN[r]);
            eN = eN + one4;
            f32x4 dd;
#pragma unroll
            for (int r = 0; r < 4; ++r) dd[r] = __builtin_amdgcn_rcpf(eN[r]);
            f32x4 ng = dd * (-2.0f) + one4;
            f32x4 hn = zg * (hprev - ng) + ng;   // exact fp32 carry
            hprev = hn;
            bf16x4 hp;
#pragma unroll
            for (int r = 0; r < 4; ++r) hp[r] = (__bf16)hn[r];
            *(bf16x4*)(Nh + wboff) = hp;         // one ds_write_b64

            // output head in the write-shadow: ALL waves compute (identical
            // streams -> no barrier straggler); each stores only its 4 rows.
            {
                f32x4 o = obias;
                o = MFMA(obhi[0], b0, o, 0, 0, 0);
                o = MFMA(obhi[1], b1, o, 0, 0, 0);
                if ((u | s) != 0 && ostorer)
                    *(float2*)(opb + (8 * u + 2 * s - 2)) = make_float2(o[0], o[1]);
            }

            __syncthreads();   // state i+1 published
        }
    }

    // final output: row 179 from state 180 (in buf 0)
    {
        const __bf16* Hh = hbuf[0];
        bf16x8 b0 = *(const bf16x8*)(Hh + rdoff);
        bf16x8 b1 = *(const bf16x8*)(Hh + rdoff + 32);
        f32x4 o = obias;
        o = MFMA(obhi[0], b0, o, 0, 0, 0);
        o = MFMA(obhi[1], b1, o, 0, 0, 0);
        if (ostorer)
            *(float2*)(opb + (SEQ - 1) * 2) = make_float2(o[0], o[1]);
    }
}

extern "C" void kernel_launch(void* const* d_in, const int* in_sizes, int n_in,
                              void* d_out, int out_size, void* d_ws, size_t ws_size,
                              hipStream_t stream) {
    (void)in_sizes; (void)n_in; (void)out_size; (void)d_ws; (void)ws_size;
    const float* z       = (const float*)d_in[0];
    const int*   labels  = (const int*)d_in[1];
    const float* embed_w = (const float*)d_in[2];
    const float* fc_w    = (const float*)d_in[3];
    const float* fc_b    = (const float*)d_in[4];
    // d_in[5] = w_ih: unused (GRU input is all zeros; b_ih carries the effect)
    const float* w_hh    = (const float*)d_in[6];
    const float* b_ih    = (const float*)d_in[7];
    const float* b_hh    = (const float*)d_in[8];
    const float* out_w   = (const float*)d_in[9];
    const float* out_b   = (const float*)d_in[10];
    float* out = (float*)d_out;

    gru_all<<<NB / MT, 256, 0, stream>>>(z, labels, embed_w, fc_w, fc_b,
                                         w_hh, b_ih, b_hh, out_w, out_b, out);
}